// Round 1
// baseline (9572.770 us; speedup 1.0000x reference)
//
#include <hip/hip_runtime.h>
#include <stdint.h>

// LSTM (B=256,T=512,I=512,H=1024) + FC on MI355X.
// Strategy: persistent 256-block kernel, 1 block/CU. Each block owns
// (jt = 32 hidden units -> 128 gate rows, bt = 32 batch rows).
// Weights (W_hh|W_ih concatenated, K=1536) live in VGPRs as MFMA B-frags
// (2 n-tiles x 48 k-steps x 4 VGPR = 384 VGPRs/wave), loaded once.
// h exchanged through global memory in MFMA-A-fragment packed order,
// double buffered; 8 independent 32-block sub-barriers (batch groups).
// c stays in fp32 registers. Final FC in fp32.

#define T_STEPS 512

typedef __bf16 bf16x8 __attribute__((ext_vector_type(8)));
typedef float  f32x4  __attribute__((ext_vector_type(4)));

__device__ __forceinline__ uint16_t f2bf(float f) {
  uint32_t u = __float_as_uint(f);
  u += 0x7fffu + ((u >> 16) & 1u);   // RNE
  return (uint16_t)(u >> 16);
}
__device__ __forceinline__ float sigmoid_f(float z) {
  return 1.0f / (1.0f + __expf(-z));
}
__device__ __forceinline__ float tanh_f(float x) {
  float ax = __builtin_fabsf(x);
  float e  = __expf(-2.0f * ax);
  float r  = (1.0f - e) / (1.0f + e);
  return __builtin_copysignf(r, x);
}

// ws layout (bytes):
//   [0, 12582912)            Wpack  : bf16 frags [jt32][w4][q2][s48][lane64][8]
//   [12582912, +134217728)   xpack  : bf16 frags [t512][bt8][ks16][mt2][lane64][8]
//   [146800640, +1048576)    hpack  : bf16 frags [phase2][bt8][jt32][mt2][lane64][8]
//   [147849216, +1048576)    hfinal : fp32 [256][1024]
//   [148897792, +4096)       counters: cnt[bt] at +bt*64B, abort flag at int 256

__global__ __launch_bounds__(256) void prep_w(const float* __restrict__ Wih,
                                              const float* __restrict__ Whh,
                                              uint16_t* __restrict__ wp,
                                              int* __restrict__ cnt) {
  if (blockIdx.x == 0) {
    for (int i = threadIdx.x; i < 1024; i += 256) cnt[i] = 0;
  }
  int idx = blockIdx.x * 256 + threadIdx.x;     // 786432 total
  int l = idx & 63;
  int r = idx >> 6;
  int s = r % 48; r /= 48;
  int q = r & 1;  r >>= 1;
  int w = r & 3;  r >>= 2;
  int jt = r;                                    // 0..31
  int row = w * 1024 + jt * 32 + q * 16 + (l & 15);
  int kb  = s * 32 + (l >> 4) * 8;               // 0..1528
  const float* src = (kb < 1024) ? (Whh + (size_t)row * 1024 + kb)
                                 : (Wih + (size_t)row * 512 + (kb - 1024));
  uint32_t d0 = (uint32_t)f2bf(src[0]) | ((uint32_t)f2bf(src[1]) << 16);
  uint32_t d1 = (uint32_t)f2bf(src[2]) | ((uint32_t)f2bf(src[3]) << 16);
  uint32_t d2 = (uint32_t)f2bf(src[4]) | ((uint32_t)f2bf(src[5]) << 16);
  uint32_t d3 = (uint32_t)f2bf(src[6]) | ((uint32_t)f2bf(src[7]) << 16);
  *(uint4*)(wp + (size_t)idx * 8) = make_uint4(d0, d1, d2, d3);
}

__global__ __launch_bounds__(256) void prep_x(const float* __restrict__ x,
                                              uint16_t* __restrict__ xp) {
  int idx = blockIdx.x * 256 + threadIdx.x;     // 8388608 total
  int l = idx & 63;
  int r = idx >> 6;
  int mt = r & 1;  r >>= 1;
  int ks = r & 15; r >>= 4;
  int bt = r & 7;  r >>= 3;
  int t  = r;                                    // 0..511
  int b = bt * 32 + mt * 16 + (l & 15);
  int k = ks * 32 + (l >> 4) * 8;
  const float* src = x + ((size_t)b * 512 + t) * 512 + k;
  uint32_t d0 = (uint32_t)f2bf(src[0]) | ((uint32_t)f2bf(src[1]) << 16);
  uint32_t d1 = (uint32_t)f2bf(src[2]) | ((uint32_t)f2bf(src[3]) << 16);
  uint32_t d2 = (uint32_t)f2bf(src[4]) | ((uint32_t)f2bf(src[5]) << 16);
  uint32_t d3 = (uint32_t)f2bf(src[6]) | ((uint32_t)f2bf(src[7]) << 16);
  *(uint4*)(xp + (size_t)idx * 8) = make_uint4(d0, d1, d2, d3);
}

// LDS: hbuf 65536 | xbuf0 32768 | xbuf1 32768 | zl [4][32][36] f32 (18432)
// total 149504 bytes. FC phase reuses bytes [0,131584) as hl[32][1028] f32.
__global__ __launch_bounds__(256, 1) void lstm_main(
    const uint16_t* __restrict__ wpack,
    const uint16_t* __restrict__ xpack,
    uint16_t* __restrict__ hpack,
    float* __restrict__ hfinal,
    int* cnt,
    const float* __restrict__ bih,
    const float* __restrict__ bhh,
    const float* __restrict__ Wfc,
    const float* __restrict__ bfc,
    float* __restrict__ out) {
  extern __shared__ char smem[];

  const int tid = threadIdx.x;
  const int w   = tid >> 6;         // wave = gate index (i,f,g,o)
  const int l   = tid & 63;
  const int jt  = blockIdx.x >> 3;  // unit tile 0..31
  const int bt  = blockIdx.x & 7;   // batch tile 0..7 (bt-group -> same XCD slot mod 8)

  char* const hbuf  = smem;
  char* const xbuf0 = smem + 65536;
  char* const xbuf1 = smem + 98304;
  float* const zl   = (float*)(smem + 131072);  // [4][32][36]

  int* const cptr   = cnt + bt * 16;
  int* const abortf = cnt + 256;

  // ---- resident B fragments: fb[q][s], s<32 -> W_hh k, s>=32 -> W_ih k ----
  bf16x8 fb[2][48];
#pragma unroll
  for (int q = 0; q < 2; ++q) {
#pragma unroll
    for (int s = 0; s < 48; ++s) {
      union { uint4 u; bf16x8 b; } cv;
      cv.u = *(const uint4*)(wpack +
              (size_t)(((jt * 4 + w) * 2 + q) * 48 + s) * 512 + (size_t)l * 8);
      fb[q][s] = cv.b;
    }
  }

  float bias0, bias1;
  {
    int u0b = jt * 32 + (l & 15);
    bias0 = bih[w * 1024 + u0b]      + bhh[w * 1024 + u0b];
    bias1 = bih[w * 1024 + u0b + 16] + bhh[w * 1024 + u0b + 16];
  }

  // cell-update mapping: all 256 threads own 4 cells
  const int umt = tid >> 7;
  const int ul  = (tid >> 1) & 63;
  const int uj  = (tid & 1) * 4;
  const int um  = umt * 16 + (ul & 15);      // batch row in tile
  const int uu0 = (ul >> 4) * 8 + uj;        // unit in tile (4 consecutive)
  float c0 = 0.f, c1 = 0.f, c2 = 0.f, c3 = 0.f;

  // prestage x(t=0)
  {
    const uint16_t* src = xpack + (size_t)bt * 16384;
#pragma unroll
    for (int i = 0; i < 8; ++i) {
      int ci = w * 8 + i;
      __builtin_amdgcn_global_load_lds(
          (const __attribute__((address_space(1))) void*)(src + (size_t)ci * 512 + (size_t)l * 8),
          (__attribute__((address_space(3))) void*)(xbuf0 + ci * 1024), 16, 0, 0);
    }
  }
  __syncthreads();

  for (int t = 0; t < T_STEPS; ++t) {
    // prefetch x(t+1) into the other x buffer (x independent of recurrence)
    if (t + 1 < T_STEPS) {
      const uint16_t* src = xpack + (size_t)((t + 1) * 8 + bt) * 16384;
      char* dst = ((t + 1) & 1) ? xbuf1 : xbuf0;
#pragma unroll
      for (int i = 0; i < 8; ++i) {
        int ci = w * 8 + i;
        __builtin_amdgcn_global_load_lds(
            (const __attribute__((address_space(1))) void*)(src + (size_t)ci * 512 + (size_t)l * 8),
            (__attribute__((address_space(3))) void*)(dst + ci * 1024), 16, 0, 0);
      }
    }

    f32x4 acc[2][2];
#pragma unroll
    for (int mt = 0; mt < 2; ++mt)
#pragma unroll
      for (int q = 0; q < 2; ++q) acc[mt][q] = (f32x4){0.f, 0.f, 0.f, 0.f};

    // x-part MFMAs (overlaps barrier wait of other blocks)
    {
      const char* xc = (t & 1) ? xbuf1 : xbuf0;
#pragma unroll
      for (int s = 0; s < 16; ++s) {
#pragma unroll
        for (int mt = 0; mt < 2; ++mt) {
          bf16x8 a = *(const bf16x8*)(xc + ((s * 2 + mt) * 64 + l) * 16);
          acc[mt][0] = __builtin_amdgcn_mfma_f32_16x16x32_bf16(a, fb[0][32 + s], acc[mt][0], 0, 0, 0);
          acc[mt][1] = __builtin_amdgcn_mfma_f32_16x16x32_bf16(a, fb[1][32 + s], acc[mt][1], 0, 0, 0);
        }
      }
    }

    if (t > 0) {
      // sub-barrier: wait until all 32 blocks of this bt-group arrived for t-1
      if (tid == 0) {
        if (__hip_atomic_load(abortf, __ATOMIC_RELAXED, __HIP_MEMORY_SCOPE_AGENT) == 0) {
          const int target = 32 * t;
          int iters = 0;
          while (__hip_atomic_load(cptr, __ATOMIC_RELAXED, __HIP_MEMORY_SCOPE_AGENT) < target) {
            __builtin_amdgcn_s_sleep(1);
            if (++iters > 4000000) {  // hang insurance
              __hip_atomic_store(abortf, 1, __ATOMIC_RELAXED, __HIP_MEMORY_SCOPE_AGENT);
              break;
            }
          }
        }
      }
      __syncthreads();
      __builtin_amdgcn_fence(__ATOMIC_ACQUIRE, "agent");
      // stage h(t-1): 64 KB, already in A-fragment order
      const uint16_t* hs = hpack + (size_t)((((t - 1) & 1) * 8 + bt)) * 32768;
#pragma unroll
      for (int i = 0; i < 16; ++i) {
        int ci = w * 16 + i;
        __builtin_amdgcn_global_load_lds(
            (const __attribute__((address_space(1))) void*)(hs + (size_t)ci * 512 + (size_t)l * 8),
            (__attribute__((address_space(3))) void*)(hbuf + ci * 1024), 16, 0, 0);
      }
      __syncthreads();
#pragma unroll
      for (int s = 0; s < 32; ++s) {
#pragma unroll
        for (int mt = 0; mt < 2; ++mt) {
          bf16x8 a = *(const bf16x8*)(hbuf + ((s * 2 + mt) * 64 + l) * 16);
          acc[mt][0] = __builtin_amdgcn_mfma_f32_16x16x32_bf16(a, fb[0][s], acc[mt][0], 0, 0, 0);
          acc[mt][1] = __builtin_amdgcn_mfma_f32_16x16x32_bf16(a, fb[1][s], acc[mt][1], 0, 0, 0);
        }
      }
    }

    // gate activation by owning wave, exchange via LDS
#pragma unroll
    for (int mt = 0; mt < 2; ++mt) {
#pragma unroll
      for (int q = 0; q < 2; ++q) {
        f32x4 v = acc[mt][q];
        float bq = q ? bias1 : bias0;
#pragma unroll
        for (int r = 0; r < 4; ++r) {
          float z = v[r] + bq;
          float a = (w == 2) ? tanh_f(z) : sigmoid_f(z);
          int m  = mt * 16 + (l >> 4) * 4 + r;   // C layout: row=(lane>>4)*4+reg
          int uu = q * 16 + (l & 15);            //           col=lane&15
          zl[(w * 32 + m) * 36 + uu] = a;
        }
      }
    }
    __syncthreads();

    // cell update (c in regs), pack h to bf16 A-fragment order, store
    {
      const f32x4 gi = *(const f32x4*)&zl[(0 * 32 + um) * 36 + uu0];
      const f32x4 gf = *(const f32x4*)&zl[(1 * 32 + um) * 36 + uu0];
      const f32x4 gg = *(const f32x4*)&zl[(2 * 32 + um) * 36 + uu0];
      const f32x4 go = *(const f32x4*)&zl[(3 * 32 + um) * 36 + uu0];
      c0 = gf[0] * c0 + gi[0] * gg[0];
      c1 = gf[1] * c1 + gi[1] * gg[1];
      c2 = gf[2] * c2 + gi[2] * gg[2];
      c3 = gf[3] * c3 + gi[3] * gg[3];
      float h0 = go[0] * tanh_f(c0);
      float h1 = go[1] * tanh_f(c1);
      float h2 = go[2] * tanh_f(c2);
      float h3 = go[3] * tanh_f(c3);
      uint32_t p0 = (uint32_t)f2bf(h0) | ((uint32_t)f2bf(h1) << 16);
      uint32_t p1 = (uint32_t)f2bf(h2) | ((uint32_t)f2bf(h3) << 16);
      uint16_t* hp = hpack +
          (size_t)((((t & 1) * 8 + bt) * 32 + jt) * 2 + umt) * 512 + (size_t)ul * 8 + uj;
      *(uint2*)hp = make_uint2(p0, p1);
      if (t == T_STEPS - 1) {
        f32x4 hv = {h0, h1, h2, h3};
        *(f32x4*)&hfinal[(size_t)(bt * 32 + um) * 1024 + jt * 32 + uu0] = hv;
      }
    }
    __syncthreads();   // all stores drained (vmcnt) before arrive
    if (tid == 0) {
      __hip_atomic_fetch_add(cptr, 1, __ATOMIC_RELEASE, __HIP_MEMORY_SCOPE_AGENT);
    }
  }

  // ---- final FC: out = hT @ Wfc^T + bfc (fp32) ----
  if (tid == 0) {
    if (__hip_atomic_load(abortf, __ATOMIC_RELAXED, __HIP_MEMORY_SCOPE_AGENT) == 0) {
      const int target = 32 * T_STEPS;
      int iters = 0;
      while (__hip_atomic_load(cptr, __ATOMIC_RELAXED, __HIP_MEMORY_SCOPE_AGENT) < target) {
        __builtin_amdgcn_s_sleep(1);
        if (++iters > 4000000) {
          __hip_atomic_store(abortf, 1, __ATOMIC_RELAXED, __HIP_MEMORY_SCOPE_AGENT);
          break;
        }
      }
    }
  }
  __syncthreads();
  __builtin_amdgcn_fence(__ATOMIC_ACQUIRE, "agent");

  float* const hl = (float*)smem;   // [32][1028] padded
#pragma unroll 4
  for (int i = 0; i < 32; ++i) {
    int d4  = i * 256 + tid;
    int row = d4 >> 8;
    int c4  = (d4 & 255) * 4;
    *(f32x4*)&hl[row * 1028 + c4] =
        *(const f32x4*)&hfinal[(size_t)(bt * 32 + row) * 1024 + c4];
  }
  __syncthreads();
  {
    const int bl = tid >> 3;
    const int oo = tid & 7;
    const int o0 = jt * 16 + oo * 2;
    float a0 = 0.f, a1 = 0.f;
    const float* hrow = &hl[bl * 1028];
    const float* w0p  = Wfc + (size_t)o0 * 1024;
    const float* w1p  = w0p + 1024;
#pragma unroll 8
    for (int k = 0; k < 1024; k += 4) {
      f32x4 hv = *(const f32x4*)&hrow[k];
      f32x4 w0 = *(const f32x4*)&w0p[k];
      f32x4 w1 = *(const f32x4*)&w1p[k];
      a0 += hv[0] * w0[0] + hv[1] * w0[1] + hv[2] * w0[2] + hv[3] * w0[3];
      a1 += hv[0] * w1[0] + hv[1] * w1[1] + hv[2] * w1[2] + hv[3] * w1[3];
    }
    int b = bt * 32 + bl;
    out[(size_t)b * 512 + o0]     = a0 + bfc[o0];
    out[(size_t)b * 512 + o0 + 1] = a1 + bfc[o0 + 1];
  }
}

extern "C" void kernel_launch(void* const* d_in, const int* in_sizes, int n_in,
                              void* d_out, int out_size, void* d_ws, size_t ws_size,
                              hipStream_t stream) {
  const float* x   = (const float*)d_in[0];
  const float* Wih = (const float*)d_in[1];
  const float* Whh = (const float*)d_in[2];
  const float* bih = (const float*)d_in[3];
  const float* bhh = (const float*)d_in[4];
  const float* Wfc = (const float*)d_in[5];
  const float* bfc = (const float*)d_in[6];
  float* out = (float*)d_out;

  char* ws = (char*)d_ws;
  uint16_t* wp  = (uint16_t*)(ws);
  uint16_t* xp  = (uint16_t*)(ws + 12582912);
  uint16_t* hp  = (uint16_t*)(ws + 146800640);
  float*    hf  = (float*)   (ws + 147849216);
  int*      cnt = (int*)     (ws + 148897792);

  (void)hipFuncSetAttribute((const void*)lstm_main,
                            hipFuncAttributeMaxDynamicSharedMemorySize, 149504);

  hipLaunchKernelGGL(prep_w, dim3(3072), dim3(256), 0, stream, Wih, Whh, wp, cnt);
  hipLaunchKernelGGL(prep_x, dim3(32768), dim3(256), 0, stream, x, xp);
  hipLaunchKernelGGL(lstm_main, dim3(256), dim3(256), 149504, stream,
                     wp, xp, hp, hf, cnt, bih, bhh, Wfc, bfc, out);
}

// Round 2
// 3691.746 us; speedup vs baseline: 2.5930x; 2.5930x over previous
//
#include <hip/hip_runtime.h>
#include <stdint.h>

// LSTM (B=256,T=512,I=512,H=1024) + FC on MI355X.
// Persistent 256-block kernel, 1 block/CU. Block owns (jt: 32 hidden units ->
// 128 gate rows, bt: 32 batch rows). Weights resident in VGPR/AGPR as MFMA
// B-frags (384 regs/wave), loaded once. h exchanged via LLC using
// L2-BYPASSING ops only (relaxed agent atomics / global_load_lds aux=SC0|SC1):
// NO agent fences in the loop (agent release/acquire = buffer_wbl2/buffer_inv
// full-L2 tag walks -> the 18 us/step stall of round 1).
// 8 independent 32-block sub-barriers (one per batch group), hand-rolled
// monotonic counters at LLC. c stays in fp32 registers. Final FC in fp32.

#define T_STEPS 512

typedef __bf16 bf16x8 __attribute__((ext_vector_type(8)));
typedef float  f32x4  __attribute__((ext_vector_type(4)));

__device__ __forceinline__ uint16_t f2bf(float f) {
  uint32_t u = __float_as_uint(f);
  u += 0x7fffu + ((u >> 16) & 1u);   // RNE
  return (uint16_t)(u >> 16);
}
__device__ __forceinline__ float sigmoid_f(float z) {
  return 1.0f / (1.0f + __expf(-z));
}
__device__ __forceinline__ float tanh_f(float x) {
  float ax = __builtin_fabsf(x);
  float e  = __expf(-2.0f * ax);
  float r  = (1.0f - e) / (1.0f + e);
  return __builtin_copysignf(r, x);
}

// ws layout (bytes):
//   [0, 12582912)            Wpack  : bf16 frags [jt32][w4][q2][s48][lane64][8]
//   [12582912, +134217728)   xpack  : bf16 frags [t512][bt8][ks16][mt2][lane64][8]
//   [146800640, +1048576)    hpack  : bf16 frags [phase2][bt8][jt32][mt2][lane64][8]
//   [147849216, +1048576)    hfinal : fp32 [256][1024]
//   [148897792, +4096)       counters: cnt[bt] at +bt*64B

__global__ __launch_bounds__(256) void prep_w(const float* __restrict__ Wih,
                                              const float* __restrict__ Whh,
                                              uint16_t* __restrict__ wp,
                                              int* __restrict__ cnt) {
  if (blockIdx.x == 0) {
    for (int i = threadIdx.x; i < 1024; i += 256)
      __hip_atomic_store(&cnt[i], 0, __ATOMIC_RELAXED, __HIP_MEMORY_SCOPE_AGENT);
  }
  int idx = blockIdx.x * 256 + threadIdx.x;     // 786432 total
  int l = idx & 63;
  int r = idx >> 6;
  int s = r % 48; r /= 48;
  int q = r & 1;  r >>= 1;
  int w = r & 3;  r >>= 2;
  int jt = r;                                    // 0..31
  int row = w * 1024 + jt * 32 + q * 16 + (l & 15);
  int kb  = s * 32 + (l >> 4) * 8;               // 0..1528
  const float* src = (kb < 1024) ? (Whh + (size_t)row * 1024 + kb)
                                 : (Wih + (size_t)row * 512 + (kb - 1024));
  uint32_t d0 = (uint32_t)f2bf(src[0]) | ((uint32_t)f2bf(src[1]) << 16);
  uint32_t d1 = (uint32_t)f2bf(src[2]) | ((uint32_t)f2bf(src[3]) << 16);
  uint32_t d2 = (uint32_t)f2bf(src[4]) | ((uint32_t)f2bf(src[5]) << 16);
  uint32_t d3 = (uint32_t)f2bf(src[6]) | ((uint32_t)f2bf(src[7]) << 16);
  *(uint4*)(wp + (size_t)idx * 8) = make_uint4(d0, d1, d2, d3);
}

__global__ __launch_bounds__(256) void prep_x(const float* __restrict__ x,
                                              uint16_t* __restrict__ xp) {
  int idx = blockIdx.x * 256 + threadIdx.x;     // 8388608 total
  int l = idx & 63;
  int r = idx >> 6;
  int mt = r & 1;  r >>= 1;
  int ks = r & 15; r >>= 4;
  int bt = r & 7;  r >>= 3;
  int t  = r;                                    // 0..511
  int b = bt * 32 + mt * 16 + (l & 15);
  int k = ks * 32 + (l >> 4) * 8;
  const float* src = x + ((size_t)b * 512 + t) * 512 + k;
  uint32_t d0 = (uint32_t)f2bf(src[0]) | ((uint32_t)f2bf(src[1]) << 16);
  uint32_t d1 = (uint32_t)f2bf(src[2]) | ((uint32_t)f2bf(src[3]) << 16);
  uint32_t d2 = (uint32_t)f2bf(src[4]) | ((uint32_t)f2bf(src[5]) << 16);
  uint32_t d3 = (uint32_t)f2bf(src[6]) | ((uint32_t)f2bf(src[7]) << 16);
  *(uint4*)(xp + (size_t)idx * 8) = make_uint4(d0, d1, d2, d3);
}

// LDS: hbuf 65536 | xbuf0 32768 | xbuf1 32768 | zl [4][32][36] f32 (18432)
// total 149504 bytes. FC phase reuses bytes [0,131584) as hl[32][1028] f32.
__global__ __launch_bounds__(256, 1) void lstm_main(
    const uint16_t* __restrict__ wpack,
    const uint16_t* __restrict__ xpack,
    uint16_t* __restrict__ hpack,
    float* __restrict__ hfinal,
    int* cnt,
    const float* __restrict__ bih,
    const float* __restrict__ bhh,
    const float* __restrict__ Wfc,
    const float* __restrict__ bfc,
    float* __restrict__ out) {
  extern __shared__ char smem[];

  const int tid = threadIdx.x;
  const int w   = tid >> 6;         // wave = gate index (i,f,g,o)
  const int l   = tid & 63;
  const int jt  = blockIdx.x >> 3;  // unit tile 0..31
  const int bt  = blockIdx.x & 7;   // batch tile 0..7

  char* const hbuf  = smem;
  char* const xbuf0 = smem + 65536;
  char* const xbuf1 = smem + 98304;
  float* const zl   = (float*)(smem + 131072);  // [4][32][36]

  int* const cptr = cnt + bt * 16;
  int spin_budget = 50000000;       // hang insurance across all spins

  // ---- resident B fragments: fb[q][s], s<32 -> W_hh k, s>=32 -> W_ih k ----
  bf16x8 fb[2][48];
#pragma unroll
  for (int q = 0; q < 2; ++q) {
#pragma unroll
    for (int s = 0; s < 48; ++s) {
      union { uint4 u; bf16x8 b; } cv;
      cv.u = *(const uint4*)(wpack +
              (size_t)(((jt * 4 + w) * 2 + q) * 48 + s) * 512 + (size_t)l * 8);
      fb[q][s] = cv.b;
    }
  }

  float bias0, bias1;
  {
    int u0b = jt * 32 + (l & 15);
    bias0 = bih[w * 1024 + u0b]      + bhh[w * 1024 + u0b];
    bias1 = bih[w * 1024 + u0b + 16] + bhh[w * 1024 + u0b + 16];
  }

  // cell-update mapping: all 256 threads own 4 cells
  const int umt = tid >> 7;
  const int ul  = (tid >> 1) & 63;
  const int uj  = (tid & 1) * 4;
  const int um  = umt * 16 + (ul & 15);      // batch row in tile
  const int uu0 = (ul >> 4) * 8 + uj;        // unit in tile (4 consecutive)
  float c0 = 0.f, c1 = 0.f, c2 = 0.f, c3 = 0.f;

  // prestage x(t=0)
  {
    const uint16_t* src = xpack + (size_t)bt * 16384;
#pragma unroll
    for (int i = 0; i < 8; ++i) {
      int ci = w * 8 + i;
      __builtin_amdgcn_global_load_lds(
          (const __attribute__((address_space(1))) void*)(src + (size_t)ci * 512 + (size_t)l * 8),
          (__attribute__((address_space(3))) void*)(xbuf0 + ci * 1024), 16, 0, 0);
    }
  }
  __syncthreads();

  for (int t = 0; t < T_STEPS; ++t) {
    // A: prefetch x(t+1) (normal caching: L2 stays warm now — no more invs)
    if (t + 1 < T_STEPS) {
      const uint16_t* src = xpack + (size_t)((t + 1) * 8 + bt) * 16384;
      char* dst = ((t + 1) & 1) ? xbuf1 : xbuf0;
#pragma unroll
      for (int i = 0; i < 8; ++i) {
        int ci = w * 8 + i;
        __builtin_amdgcn_global_load_lds(
            (const __attribute__((address_space(1))) void*)(src + (size_t)ci * 512 + (size_t)l * 8),
            (__attribute__((address_space(3))) void*)(dst + ci * 1024), 16, 0, 0);
      }
    }

    f32x4 acc[2][2];
#pragma unroll
    for (int mt = 0; mt < 2; ++mt)
#pragma unroll
      for (int q = 0; q < 2; ++q) acc[mt][q] = (f32x4){0.f, 0.f, 0.f, 0.f};

    const char* xc = (t & 1) ? xbuf1 : xbuf0;

    // B: x-part MFMAs, first half (hides producer-side jitter)
#pragma unroll
    for (int s = 0; s < 8; ++s) {
#pragma unroll
      for (int mt = 0; mt < 2; ++mt) {
        bf16x8 a = *(const bf16x8*)(xc + ((s * 2 + mt) * 64 + l) * 16);
        acc[mt][0] = __builtin_amdgcn_mfma_f32_16x16x32_bf16(a, fb[0][32 + s], acc[mt][0], 0, 0, 0);
        acc[mt][1] = __builtin_amdgcn_mfma_f32_16x16x32_bf16(a, fb[1][32 + s], acc[mt][1], 0, 0, 0);
      }
    }

    // C: group barrier for h(t-1), then issue LLC-bypass h loads
    if (t > 0) {
      if (tid == 0) {
        const int target = 32 * t;
        while (__hip_atomic_load(cptr, __ATOMIC_RELAXED, __HIP_MEMORY_SCOPE_AGENT) < target) {
          if (--spin_budget < 0) break;
          __builtin_amdgcn_s_sleep(1);
        }
      }
      __syncthreads();
      const uint16_t* hs = hpack + (size_t)(((t - 1) & 1) * 8 + bt) * 32768;
#pragma unroll
      for (int i = 0; i < 16; ++i) {
        int ci = w * 16 + i;
        // aux=17 = SC0|SC1: bypass L1+L2, read at LLC (the coherence point).
        __builtin_amdgcn_global_load_lds(
            (const __attribute__((address_space(1))) void*)(hs + (size_t)ci * 512 + (size_t)l * 8),
            (__attribute__((address_space(3))) void*)(hbuf + ci * 1024), 16, 0, 17);
      }
    }

    // D: x-part MFMAs, second half (overlaps in-flight h loads)
#pragma unroll
    for (int s = 8; s < 16; ++s) {
#pragma unroll
      for (int mt = 0; mt < 2; ++mt) {
        bf16x8 a = *(const bf16x8*)(xc + ((s * 2 + mt) * 64 + l) * 16);
        acc[mt][0] = __builtin_amdgcn_mfma_f32_16x16x32_bf16(a, fb[0][32 + s], acc[mt][0], 0, 0, 0);
        acc[mt][1] = __builtin_amdgcn_mfma_f32_16x16x32_bf16(a, fb[1][32 + s], acc[mt][1], 0, 0, 0);
      }
    }

    // E: drain loads (h + next-x), then h-part MFMAs
    __syncthreads();
    if (t > 0) {
#pragma unroll
      for (int s = 0; s < 32; ++s) {
#pragma unroll
        for (int mt = 0; mt < 2; ++mt) {
          bf16x8 a = *(const bf16x8*)(hbuf + ((s * 2 + mt) * 64 + l) * 16);
          acc[mt][0] = __builtin_amdgcn_mfma_f32_16x16x32_bf16(a, fb[0][s], acc[mt][0], 0, 0, 0);
          acc[mt][1] = __builtin_amdgcn_mfma_f32_16x16x32_bf16(a, fb[1][s], acc[mt][1], 0, 0, 0);
        }
      }
    }

    // G: gate activation by owning wave, exchange via LDS
#pragma unroll
    for (int mt = 0; mt < 2; ++mt) {
#pragma unroll
      for (int q = 0; q < 2; ++q) {
        f32x4 v = acc[mt][q];
        float bq = q ? bias1 : bias0;
#pragma unroll
        for (int r = 0; r < 4; ++r) {
          float z = v[r] + bq;
          float a = (w == 2) ? tanh_f(z) : sigmoid_f(z);
          int m  = mt * 16 + (l >> 4) * 4 + r;   // C layout: row=(lane>>4)*4+reg
          int uu = q * 16 + (l & 15);            //           col=lane&15
          zl[(w * 32 + m) * 36 + uu] = a;
        }
      }
    }
    __syncthreads();  // H

    // I: cell update (c in regs), pack h, LLC-resident atomic stores
    {
      const f32x4 gi = *(const f32x4*)&zl[(0 * 32 + um) * 36 + uu0];
      const f32x4 gf = *(const f32x4*)&zl[(1 * 32 + um) * 36 + uu0];
      const f32x4 gg = *(const f32x4*)&zl[(2 * 32 + um) * 36 + uu0];
      const f32x4 go = *(const f32x4*)&zl[(3 * 32 + um) * 36 + uu0];
      c0 = gf[0] * c0 + gi[0] * gg[0];
      c1 = gf[1] * c1 + gi[1] * gg[1];
      c2 = gf[2] * c2 + gi[2] * gg[2];
      c3 = gf[3] * c3 + gi[3] * gg[3];
      float h0 = go[0] * tanh_f(c0);
      float h1 = go[1] * tanh_f(c1);
      float h2 = go[2] * tanh_f(c2);
      float h3 = go[3] * tanh_f(c3);
      uint32_t p0 = (uint32_t)f2bf(h0) | ((uint32_t)f2bf(h1) << 16);
      uint32_t p1 = (uint32_t)f2bf(h2) | ((uint32_t)f2bf(h3) << 16);
      unsigned long long pv = ((unsigned long long)p1 << 32) | (unsigned long long)p0;
      uint16_t* hp = hpack +
          (size_t)((((t & 1) * 8 + bt) * 32 + jt) * 2 + umt) * 512 + (size_t)ul * 8 + uj;
      __hip_atomic_store((unsigned long long*)hp, pv,
                         __ATOMIC_RELAXED, __HIP_MEMORY_SCOPE_AGENT);
      if (t == T_STEPS - 1) {
        unsigned long long q0 = ((unsigned long long)__float_as_uint(h1) << 32) |
                                (unsigned long long)__float_as_uint(h0);
        unsigned long long q1 = ((unsigned long long)__float_as_uint(h3) << 32) |
                                (unsigned long long)__float_as_uint(h2);
        unsigned long long* fp = (unsigned long long*)
            &hfinal[(size_t)(bt * 32 + um) * 1024 + jt * 32 + uu0];
        __hip_atomic_store(fp,     q0, __ATOMIC_RELAXED, __HIP_MEMORY_SCOPE_AGENT);
        __hip_atomic_store(fp + 1, q1, __ATOMIC_RELAXED, __HIP_MEMORY_SCOPE_AGENT);
      }
    }

    // J: all stores at LLC before arrive; relaxed RMW executes at LLC.
    asm volatile("s_waitcnt vmcnt(0)" ::: "memory");
    __syncthreads();
    if (tid == 0) {
      __hip_atomic_fetch_add(cptr, 1, __ATOMIC_RELAXED, __HIP_MEMORY_SCOPE_AGENT);
    }
  }

  // ---- final FC: out = hT @ Wfc^T + bfc (fp32) ----
  if (tid == 0) {
    const int target = 32 * T_STEPS;
    while (__hip_atomic_load(cptr, __ATOMIC_RELAXED, __HIP_MEMORY_SCOPE_AGENT) < target) {
      if (--spin_budget < 0) break;
      __builtin_amdgcn_s_sleep(1);
    }
  }
  __syncthreads();

  float* const hl = (float*)smem;   // [32][1028] padded
  {
    const unsigned long long* hq =
        (const unsigned long long*)(hfinal + (size_t)bt * 32 * 1024);
#pragma unroll 4
    for (int i = 0; i < 64; ++i) {
      int d   = i * 256 + tid;      // 0..16383
      int row = d >> 9;
      int c2  = d & 511;
      unsigned long long v = __hip_atomic_load(hq + (size_t)row * 512 + c2,
                                               __ATOMIC_RELAXED, __HIP_MEMORY_SCOPE_AGENT);
      *(unsigned long long*)&hl[row * 1028 + c2 * 2] = v;
    }
  }
  __syncthreads();
  {
    const int bl = tid >> 3;
    const int oo = tid & 7;
    const int o0 = jt * 16 + oo * 2;
    float a0 = 0.f, a1 = 0.f;
    const float* hrow = &hl[bl * 1028];
    const float* w0p  = Wfc + (size_t)o0 * 1024;
    const float* w1p  = w0p + 1024;
#pragma unroll 8
    for (int k = 0; k < 1024; k += 4) {
      f32x4 hv = *(const f32x4*)&hrow[k];
      f32x4 w0 = *(const f32x4*)&w0p[k];
      f32x4 w1 = *(const f32x4*)&w1p[k];
      a0 += hv[0] * w0[0] + hv[1] * w0[1] + hv[2] * w0[2] + hv[3] * w0[3];
      a1 += hv[0] * w1[0] + hv[1] * w1[1] + hv[2] * w1[2] + hv[3] * w1[3];
    }
    int b = bt * 32 + bl;
    out[(size_t)b * 512 + o0]     = a0 + bfc[o0];
    out[(size_t)b * 512 + o0 + 1] = a1 + bfc[o0 + 1];
  }
}

extern "C" void kernel_launch(void* const* d_in, const int* in_sizes, int n_in,
                              void* d_out, int out_size, void* d_ws, size_t ws_size,
                              hipStream_t stream) {
  const float* x   = (const float*)d_in[0];
  const float* Wih = (const float*)d_in[1];
  const float* Whh = (const float*)d_in[2];
  const float* bih = (const float*)d_in[3];
  const float* bhh = (const float*)d_in[4];
  const float* Wfc = (const float*)d_in[5];
  const float* bfc = (const float*)d_in[6];
  float* out = (float*)d_out;

  char* ws = (char*)d_ws;
  uint16_t* wp  = (uint16_t*)(ws);
  uint16_t* xp  = (uint16_t*)(ws + 12582912);
  uint16_t* hp  = (uint16_t*)(ws + 146800640);
  float*    hf  = (float*)   (ws + 147849216);
  int*      cnt = (int*)     (ws + 148897792);

  (void)hipFuncSetAttribute((const void*)lstm_main,
                            hipFuncAttributeMaxDynamicSharedMemorySize, 149504);

  hipLaunchKernelGGL(prep_w, dim3(3072), dim3(256), 0, stream, Wih, Whh, wp, cnt);
  hipLaunchKernelGGL(prep_x, dim3(32768), dim3(256), 0, stream, x, xp);
  hipLaunchKernelGGL(lstm_main, dim3(256), dim3(256), 149504, stream,
                     wp, xp, hp, hf, cnt, bih, bhh, Wfc, bfc, out);
}

// Round 6
// 3681.549 us; speedup vs baseline: 2.6002x; 1.0028x over previous
//
#include <hip/hip_runtime.h>
#include <stdint.h>

// LSTM (B=256,T=512,I=512,H=1024) + FC on MI355X.
// Persistent 256-block kernel, 1 block/CU. Block owns (jt: 32 hidden units ->
// 128 gate rows, bt: 32 batch rows). Weights resident as MFMA B-frags
// (384 regs/wave), loaded once. h exchanged via LLC using ONLY r2-proven
// idioms: agent-scope relaxed atomic stores (sc0 sc1, land at LLC),
// global_load_lds aux=17 (SC0|SC1, read at LLC), agent-scope relaxed loads.
// ROUND 6: the r2 counter barrier (32 same-line fetch_adds/step/group,
// serialized RMW at LLC) is replaced by PER-PRODUCER FLAGS: each producer
// stores flag[jt]=t+1 on its own 64B line (no RMW, no contention); consumers
// poll all 32 flags with one 32-lane vector load + __all. XCD-local exchange
// (r3-r5) is abandoned: the no-sc/sc0 atomic idioms provably never became
// visible at the XCD L2 (barrier timeouts tracked the spin budget).
// No agent fences anywhere in the loop. c stays in fp32 registers. FC fp32.

#define T_STEPS 512

typedef __bf16 bf16x8 __attribute__((ext_vector_type(8)));
typedef float  f32x4  __attribute__((ext_vector_type(4)));

__device__ __forceinline__ uint16_t f2bf(float f) {
  uint32_t u = __float_as_uint(f);
  u += 0x7fffu + ((u >> 16) & 1u);   // RNE
  return (uint16_t)(u >> 16);
}
__device__ __forceinline__ float sigmoid_f(float z) {
  return 1.0f / (1.0f + __expf(-z));
}
__device__ __forceinline__ float tanh_f(float x) {
  float ax = __builtin_fabsf(x);
  float e  = __expf(-2.0f * ax);
  float r  = (1.0f - e) / (1.0f + e);
  return __builtin_copysignf(r, x);
}

// ws layout (bytes):
//   [0, 12582912)            Wpack  : bf16 frags [jt32][w4][q2][s48][lane64][8]
//   [12582912, +134217728)   xpack  : bf16 frags [t512][bt8][ks16][mt2][lane64][8]
//   [146800640, +1048576)    hpack  : bf16 frags [phase2][bt8][jt32][mt2][lane64][8]
//   [147849216, +1048576)    hfinal : fp32 [256][1024]
//   [148897792, +16384)      flags  : int flag[bt][jt] at ((bt*32+jt)*16)*4B
//                            (one 64B line per producer; value = steps done)

__global__ __launch_bounds__(256) void prep_w(const float* __restrict__ Wih,
                                              const float* __restrict__ Whh,
                                              uint16_t* __restrict__ wp,
                                              int* __restrict__ flags) {
  if (blockIdx.x < 16) {
    __hip_atomic_store(&flags[blockIdx.x * 256 + threadIdx.x], 0,
                       __ATOMIC_RELAXED, __HIP_MEMORY_SCOPE_AGENT);
  }
  int idx = blockIdx.x * 256 + threadIdx.x;     // 786432 total
  int l = idx & 63;
  int r = idx >> 6;
  int s = r % 48; r /= 48;
  int q = r & 1;  r >>= 1;
  int w = r & 3;  r >>= 2;
  int jt = r;                                    // 0..31
  int row = w * 1024 + jt * 32 + q * 16 + (l & 15);
  int kb  = s * 32 + (l >> 4) * 8;               // 0..1528
  const float* src = (kb < 1024) ? (Whh + (size_t)row * 1024 + kb)
                                 : (Wih + (size_t)row * 512 + (kb - 1024));
  uint32_t d0 = (uint32_t)f2bf(src[0]) | ((uint32_t)f2bf(src[1]) << 16);
  uint32_t d1 = (uint32_t)f2bf(src[2]) | ((uint32_t)f2bf(src[3]) << 16);
  uint32_t d2 = (uint32_t)f2bf(src[4]) | ((uint32_t)f2bf(src[5]) << 16);
  uint32_t d3 = (uint32_t)f2bf(src[6]) | ((uint32_t)f2bf(src[7]) << 16);
  *(uint4*)(wp + (size_t)idx * 8) = make_uint4(d0, d1, d2, d3);
}

__global__ __launch_bounds__(256) void prep_x(const float* __restrict__ x,
                                              uint16_t* __restrict__ xp) {
  int idx = blockIdx.x * 256 + threadIdx.x;     // 8388608 total
  int l = idx & 63;
  int r = idx >> 6;
  int mt = r & 1;  r >>= 1;
  int ks = r & 15; r >>= 4;
  int bt = r & 7;  r >>= 3;
  int t  = r;                                    // 0..511
  int b = bt * 32 + mt * 16 + (l & 15);
  int k = ks * 32 + (l >> 4) * 8;
  const float* src = x + ((size_t)b * 512 + t) * 512 + k;
  uint32_t d0 = (uint32_t)f2bf(src[0]) | ((uint32_t)f2bf(src[1]) << 16);
  uint32_t d1 = (uint32_t)f2bf(src[2]) | ((uint32_t)f2bf(src[3]) << 16);
  uint32_t d2 = (uint32_t)f2bf(src[4]) | ((uint32_t)f2bf(src[5]) << 16);
  uint32_t d3 = (uint32_t)f2bf(src[6]) | ((uint32_t)f2bf(src[7]) << 16);
  *(uint4*)(xp + (size_t)idx * 8) = make_uint4(d0, d1, d2, d3);
}

// LDS: hbuf 65536 | xbuf0 32768 | xbuf1 32768 | zl [4][32][36] f32 (18432)
// total 149504 dynamic. FC phase reuses bytes [0,131584) as hl[32][1028] f32.
__global__ __launch_bounds__(256, 1) void lstm_main(
    const uint16_t* __restrict__ wpack,
    const uint16_t* __restrict__ xpack,
    uint16_t* __restrict__ hpack,
    float* __restrict__ hfinal,
    int* flags,
    const float* __restrict__ bih,
    const float* __restrict__ bhh,
    const float* __restrict__ Wfc,
    const float* __restrict__ bfc,
    float* __restrict__ out) {
  extern __shared__ char smem[];

  const int tid = threadIdx.x;
  const int w   = tid >> 6;         // wave = gate index (i,f,g,o)
  const int l   = tid & 63;
  const int jt  = blockIdx.x >> 3;  // unit tile 0..31
  const int bt  = blockIdx.x & 7;   // batch tile 0..7

  char* const hbuf  = smem;
  char* const xbuf0 = smem + 65536;
  char* const xbuf1 = smem + 98304;
  float* const zl   = (float*)(smem + 131072);  // [4][32][36]

  // per-producer flag line this block owns, and the flag line lane l polls
  int* const flag_self = flags + ((bt * 32 + jt) << 4);
  const int* const flag_poll = flags + ((bt * 32 + (l & 31)) << 4);
  int spin_budget = 2000000;        // hang insurance across all spins

  // ---- resident B fragments: fb[q][s], s<32 -> W_hh k, s>=32 -> W_ih k ----
  bf16x8 fb[2][48];
#pragma unroll
  for (int q = 0; q < 2; ++q) {
#pragma unroll
    for (int s = 0; s < 48; ++s) {
      union { uint4 u; bf16x8 b; } cv;
      cv.u = *(const uint4*)(wpack +
              (size_t)(((jt * 4 + w) * 2 + q) * 48 + s) * 512 + (size_t)l * 8);
      fb[q][s] = cv.b;
    }
  }

  float bias0, bias1;
  {
    int u0b = jt * 32 + (l & 15);
    bias0 = bih[w * 1024 + u0b]      + bhh[w * 1024 + u0b];
    bias1 = bih[w * 1024 + u0b + 16] + bhh[w * 1024 + u0b + 16];
  }

  // cell-update mapping: all 256 threads own 4 cells
  const int umt = tid >> 7;
  const int ul  = (tid >> 1) & 63;
  const int uj  = (tid & 1) * 4;
  const int um  = umt * 16 + (ul & 15);      // batch row in tile
  const int uu0 = (ul >> 4) * 8 + uj;        // unit in tile (4 consecutive)
  float c0 = 0.f, c1 = 0.f, c2 = 0.f, c3 = 0.f;

  // prestage x(t=0)
  {
    const uint16_t* src = xpack + (size_t)bt * 16384;
#pragma unroll
    for (int i = 0; i < 8; ++i) {
      int ci = w * 8 + i;
      __builtin_amdgcn_global_load_lds(
          (const __attribute__((address_space(1))) void*)(src + (size_t)ci * 512 + (size_t)l * 8),
          (__attribute__((address_space(3))) void*)(xbuf0 + ci * 1024), 16, 0, 0);
    }
  }
  __syncthreads();

  for (int t = 0; t < T_STEPS; ++t) {
    // A: prefetch x(t+1) (normal caching — xpack stays warm in L2)
    if (t + 1 < T_STEPS) {
      const uint16_t* src = xpack + (size_t)((t + 1) * 8 + bt) * 16384;
      char* dst = ((t + 1) & 1) ? xbuf1 : xbuf0;
#pragma unroll
      for (int i = 0; i < 8; ++i) {
        int ci = w * 8 + i;
        __builtin_amdgcn_global_load_lds(
            (const __attribute__((address_space(1))) void*)(src + (size_t)ci * 512 + (size_t)l * 8),
            (__attribute__((address_space(3))) void*)(dst + ci * 1024), 16, 0, 0);
      }
    }

    f32x4 acc[2][2];
#pragma unroll
    for (int mt = 0; mt < 2; ++mt)
#pragma unroll
      for (int q = 0; q < 2; ++q) acc[mt][q] = (f32x4){0.f, 0.f, 0.f, 0.f};

    const char* xc = (t & 1) ? xbuf1 : xbuf0;

    // B: x-part MFMAs, first half (hides producer-side jitter)
#pragma unroll
    for (int s = 0; s < 8; ++s) {
#pragma unroll
      for (int mt = 0; mt < 2; ++mt) {
        bf16x8 a = *(const bf16x8*)(xc + ((s * 2 + mt) * 64 + l) * 16);
        acc[mt][0] = __builtin_amdgcn_mfma_f32_16x16x32_bf16(a, fb[0][32 + s], acc[mt][0], 0, 0, 0);
        acc[mt][1] = __builtin_amdgcn_mfma_f32_16x16x32_bf16(a, fb[1][32 + s], acc[mt][1], 0, 0, 0);
      }
    }

    // C: flag barrier for h(t-1) — 32-lane parallel poll, no RMW anywhere.
    // flag[j] >= t  <=>  producer j finished step t-1 (incl. its h reads).
    if (t > 0) {
      if (tid < 64) {
        for (;;) {
          int v = __hip_atomic_load(flag_poll, __ATOMIC_RELAXED,
                                    __HIP_MEMORY_SCOPE_AGENT);
          if (__all(v >= t)) break;
          if (--spin_budget < 0) break;
          __builtin_amdgcn_s_sleep(1);
        }
      }
      __syncthreads();
      const uint16_t* hs = hpack + (size_t)(((t - 1) & 1) * 8 + bt) * 32768;
#pragma unroll
      for (int i = 0; i < 16; ++i) {
        int ci = w * 16 + i;
        // aux=17 = SC0|SC1: bypass L1+L2, read at LLC (the coherence point).
        __builtin_amdgcn_global_load_lds(
            (const __attribute__((address_space(1))) void*)(hs + (size_t)ci * 512 + (size_t)l * 8),
            (__attribute__((address_space(3))) void*)(hbuf + ci * 1024), 16, 0, 17);
      }
    }

    // D: x-part MFMAs, second half (overlaps in-flight h loads)
#pragma unroll
    for (int s = 8; s < 16; ++s) {
#pragma unroll
      for (int mt = 0; mt < 2; ++mt) {
        bf16x8 a = *(const bf16x8*)(xc + ((s * 2 + mt) * 64 + l) * 16);
        acc[mt][0] = __builtin_amdgcn_mfma_f32_16x16x32_bf16(a, fb[0][32 + s], acc[mt][0], 0, 0, 0);
        acc[mt][1] = __builtin_amdgcn_mfma_f32_16x16x32_bf16(a, fb[1][32 + s], acc[mt][1], 0, 0, 0);
      }
    }

    // E: drain loads (h + next-x), then h-part MFMAs
    __syncthreads();
    if (t > 0) {
#pragma unroll
      for (int s = 0; s < 32; ++s) {
#pragma unroll
        for (int mt = 0; mt < 2; ++mt) {
          bf16x8 a = *(const bf16x8*)(hbuf + ((s * 2 + mt) * 64 + l) * 16);
          acc[mt][0] = __builtin_amdgcn_mfma_f32_16x16x32_bf16(a, fb[0][s], acc[mt][0], 0, 0, 0);
          acc[mt][1] = __builtin_amdgcn_mfma_f32_16x16x32_bf16(a, fb[1][s], acc[mt][1], 0, 0, 0);
        }
      }
    }

    // G: gate activation by owning wave, exchange via LDS
#pragma unroll
    for (int mt = 0; mt < 2; ++mt) {
#pragma unroll
      for (int q = 0; q < 2; ++q) {
        f32x4 v = acc[mt][q];
        float bq = q ? bias1 : bias0;
#pragma unroll
        for (int r = 0; r < 4; ++r) {
          float z = v[r] + bq;
          float a = (w == 2) ? tanh_f(z) : sigmoid_f(z);
          int m  = mt * 16 + (l >> 4) * 4 + r;   // C layout: row=(lane>>4)*4+reg
          int uu = q * 16 + (l & 15);            //           col=lane&15
          zl[(w * 32 + m) * 36 + uu] = a;
        }
      }
    }
    __syncthreads();  // H

    // I: cell update (c in regs), pack h, LLC-resident agent stores
    {
      const f32x4 gi = *(const f32x4*)&zl[(0 * 32 + um) * 36 + uu0];
      const f32x4 gf = *(const f32x4*)&zl[(1 * 32 + um) * 36 + uu0];
      const f32x4 gg = *(const f32x4*)&zl[(2 * 32 + um) * 36 + uu0];
      const f32x4 go = *(const f32x4*)&zl[(3 * 32 + um) * 36 + uu0];
      c0 = gf[0] * c0 + gi[0] * gg[0];
      c1 = gf[1] * c1 + gi[1] * gg[1];
      c2 = gf[2] * c2 + gi[2] * gg[2];
      c3 = gf[3] * c3 + gi[3] * gg[3];
      float h0 = go[0] * tanh_f(c0);
      float h1 = go[1] * tanh_f(c1);
      float h2 = go[2] * tanh_f(c2);
      float h3 = go[3] * tanh_f(c3);
      uint32_t p0 = (uint32_t)f2bf(h0) | ((uint32_t)f2bf(h1) << 16);
      uint32_t p1 = (uint32_t)f2bf(h2) | ((uint32_t)f2bf(h3) << 16);
      unsigned long long pv = ((unsigned long long)p1 << 32) | (unsigned long long)p0;
      uint16_t* hp = hpack +
          (size_t)((((t & 1) * 8 + bt) * 32 + jt) * 2 + umt) * 512 + (size_t)ul * 8 + uj;
      __hip_atomic_store((unsigned long long*)hp, pv,
                         __ATOMIC_RELAXED, __HIP_MEMORY_SCOPE_AGENT);
      if (t == T_STEPS - 1) {
        unsigned long long q0 = ((unsigned long long)__float_as_uint(h1) << 32) |
                                (unsigned long long)__float_as_uint(h0);
        unsigned long long q1 = ((unsigned long long)__float_as_uint(h3) << 32) |
                                (unsigned long long)__float_as_uint(h2);
        unsigned long long* fp = (unsigned long long*)
            &hfinal[(size_t)(bt * 32 + um) * 1024 + jt * 32 + uu0];
        __hip_atomic_store(fp,     q0, __ATOMIC_RELAXED, __HIP_MEMORY_SCOPE_AGENT);
        __hip_atomic_store(fp + 1, q1, __ATOMIC_RELAXED, __HIP_MEMORY_SCOPE_AGENT);
      }
    }

    // J: all stores at LLC (vmcnt(0) per wave, joined by the barrier), then
    // announce: flag = t+1 via a plain agent store on this block's own line.
    asm volatile("s_waitcnt vmcnt(0)" ::: "memory");
    __syncthreads();
    if (tid == 0) {
      __hip_atomic_store(flag_self, t + 1, __ATOMIC_RELAXED,
                         __HIP_MEMORY_SCOPE_AGENT);
    }
  }

  // ---- final FC: out = hT @ Wfc^T + bfc (fp32) ----
  if (tid < 64) {
    for (;;) {
      int v = __hip_atomic_load(flag_poll, __ATOMIC_RELAXED,
                                __HIP_MEMORY_SCOPE_AGENT);
      if (__all(v >= T_STEPS)) break;
      if (--spin_budget < 0) break;
      __builtin_amdgcn_s_sleep(1);
    }
  }
  __syncthreads();

  float* const hl = (float*)smem;   // [32][1028] padded
  {
    const unsigned long long* hq =
        (const unsigned long long*)(hfinal + (size_t)bt * 32 * 1024);
#pragma unroll 4
    for (int i = 0; i < 64; ++i) {
      int d   = i * 256 + tid;      // 0..16383
      int row = d >> 9;
      int c2  = d & 511;
      unsigned long long v = __hip_atomic_load(hq + (size_t)row * 512 + c2,
                                               __ATOMIC_RELAXED, __HIP_MEMORY_SCOPE_AGENT);
      *(unsigned long long*)&hl[row * 1028 + c2 * 2] = v;
    }
  }
  __syncthreads();
  {
    const int bl = tid >> 3;
    const int oo = tid & 7;
    const int o0 = jt * 16 + oo * 2;
    float a0 = 0.f, a1 = 0.f;
    const float* hrow = &hl[bl * 1028];
    const float* w0p  = Wfc + (size_t)o0 * 1024;
    const float* w1p  = w0p + 1024;
#pragma unroll 8
    for (int k = 0; k < 1024; k += 4) {
      f32x4 hv = *(const f32x4*)&hrow[k];
      f32x4 w0 = *(const f32x4*)&w0p[k];
      f32x4 w1 = *(const f32x4*)&w1p[k];
      a0 += hv[0] * w0[0] + hv[1] * w0[1] + hv[2] * w0[2] + hv[3] * w0[3];
      a1 += hv[0] * w1[0] + hv[1] * w1[1] + hv[2] * w1[2] + hv[3] * w1[3];
    }
    int b = bt * 32 + bl;
    out[(size_t)b * 512 + o0]     = a0 + bfc[o0];
    out[(size_t)b * 512 + o0 + 1] = a1 + bfc[o0 + 1];
  }
}

extern "C" void kernel_launch(void* const* d_in, const int* in_sizes, int n_in,
                              void* d_out, int out_size, void* d_ws, size_t ws_size,
                              hipStream_t stream) {
  const float* x   = (const float*)d_in[0];
  const float* Wih = (const float*)d_in[1];
  const float* Whh = (const float*)d_in[2];
  const float* bih = (const float*)d_in[3];
  const float* bhh = (const float*)d_in[4];
  const float* Wfc = (const float*)d_in[5];
  const float* bfc = (const float*)d_in[6];
  float* out = (float*)d_out;

  char* ws = (char*)d_ws;
  uint16_t* wp  = (uint16_t*)(ws);
  uint16_t* xp  = (uint16_t*)(ws + 12582912);
  uint16_t* hp  = (uint16_t*)(ws + 146800640);
  float*    hf  = (float*)   (ws + 147849216);
  int*      fl  = (int*)     (ws + 148897792);

  (void)hipFuncSetAttribute((const void*)lstm_main,
                            hipFuncAttributeMaxDynamicSharedMemorySize, 149504);

  hipLaunchKernelGGL(prep_w, dim3(3072), dim3(256), 0, stream, Wih, Whh, wp, fl);
  hipLaunchKernelGGL(prep_x, dim3(32768), dim3(256), 0, stream, x, xp);
  hipLaunchKernelGGL(lstm_main, dim3(256), dim3(256), 149504, stream,
                     wp, xp, hp, hf, fl, bih, bhh, Wfc, bfc, out);
}